// Round 12
// baseline (527.246 us; speedup 1.0000x reference)
//
#include <hip/hip_runtime.h>
#include <stdint.h>

#define N_TOTAL 21840
#define NA      21888          // N_TOTAL rounded up to multiple of 64
#define W_MAX   342            // ceil(21840/64)
#define TOT_ENT 3753792u       // 64 * (342*343/2)  triangular CSR capacity
#define NMS_TH  0.3f
#define FINAL_TH 0.5f
#define NSLICE  8              // rank range-split factor

struct Inputs { const float* cls[6]; const float* reg[6]; };

// Closed-form CSR row base: row r (sorted pos) owns 342-(r>>6) slots.
__device__ __forceinline__ unsigned rowbase_u(unsigned r) {
  unsigned w = r >> 6, l = r & 63u;
  return 64u * (342u * w - (w * (w - 1u)) / 2u) + l * (342u - w);
}

// ---------------------------------------------------------------- decode ----
__global__ void decode_kernel(Inputs in,
                              float* __restrict__ dx1, float* __restrict__ dy1,
                              float* __restrict__ dx2, float* __restrict__ dy2,
                              float* __restrict__ dsc,
                              unsigned long long* __restrict__ ckey,
                              unsigned int* __restrict__ Mc,
                              unsigned int* __restrict__ rank32,
                              unsigned int* __restrict__ cnt,
                              unsigned int* __restrict__ st,
                              float* __restrict__ out) {
#pragma clang fp contract(off)
  int gid = blockIdx.x * blockDim.x + threadIdx.x;
  if (gid >= N_TOTAL) return;
  rank32[gid] = 0u;
  cnt[gid] = 0u;
  st[gid] = 0u;
  if (gid < NA - N_TOTAL) { cnt[N_TOTAL + gid] = 0u; st[N_TOTAL + gid] = 0u; }
  int sc, local;
  if      (gid < 16384) { sc = 0; local = gid;         }
  else if (gid < 20480) { sc = 1; local = gid - 16384; }
  else if (gid < 21504) { sc = 2; local = gid - 20480; }
  else if (gid < 21760) { sc = 3; local = gid - 21504; }
  else if (gid < 21824) { sc = 4; local = gid - 21760; }
  else                  { sc = 5; local = gid - 21824; }
  const int Wd = 128 >> sc, stride = 4 << sc, HW = Wd * Wd;
  const int x = local & (Wd - 1), y = local >> (7 - sc);
  const float* cls = in.cls[sc];
  const float* reg = in.reg[sc];
  float c0 = cls[local], c1 = cls[HW + local];
  float m  = fmaxf(c0, c1);
  float e0 = expf(c0 - m), e1 = expf(c1 - m);
  float prob = e1 / (e0 + e1);
  float l0 = reg[local], l1 = reg[HW + local];
  float l2 = reg[2 * HW + local], l3 = reg[3 * HW + local];
  float sF  = (float)stride;
  float pcx = 0.5f * sF + (float)x * sF;
  float pcy = 0.5f * sF + (float)y * sF;
  float pwh = sF * 4.0f;
  float cx = pcx + ((l0 * 0.1f) * pwh);
  float cy = pcy + ((l1 * 0.1f) * pwh);
  float w  = pwh * expf(l2 * 0.2f);
  float h  = pwh * expf(l3 * 0.2f);
  float x1 = cx - w * 0.5f, y1 = cy - h * 0.5f;
  float x2 = x1 + w, y2 = y1 + h;
  dx1[gid] = x1; dy1[gid] = y1; dx2[gid] = x2; dy2[gid] = y2; dsc[gid] = prob;
  out[gid * 5 + 0] = 0.0f; out[gid * 5 + 1] = 0.0f; out[gid * 5 + 2] = 0.0f;
  out[gid * 5 + 3] = 0.0f; out[gid * 5 + 4] = 0.0f;
  // Only boxes with score > FINAL_TH can affect the output (suppression only
  // flows downward in score order, and only >FINAL_TH rows are exposed).
  if (prob > FINAL_TH) {
    unsigned int pos = atomicAdd(Mc, 1u);
    ckey[pos] = ((unsigned long long)__float_as_uint(prob) << 32) |
                (unsigned int)(~(unsigned int)gid);
  }
}

// ---------------------------------------------------------------- rank ------
// Count-rank with 8-way key-range split; packed atomicAdd join (measured-good).
__global__ void __launch_bounds__(256)
rank_kernel(const unsigned long long* __restrict__ ckey,
            const unsigned int* __restrict__ Mc,
            const float* __restrict__ dx1, const float* __restrict__ dy1,
            const float* __restrict__ dx2, const float* __restrict__ dy2,
            float* __restrict__ sx1, float* __restrict__ sy1,
            float* __restrict__ sx2, float* __restrict__ sy2,
            unsigned int* __restrict__ sorig,
            unsigned int* __restrict__ rank32) {
  __shared__ unsigned long long tile[256];
  const unsigned int M = *Mc;
  if (blockIdx.x * 256u >= M) return;
  const int t = (int)threadIdx.x;
  const int p = (int)blockIdx.x * 256 + t;
  unsigned long long mykey = (p < (int)M) ? ckey[p] : 0ull;
  const int S  = (int)((M + NSLICE - 1) / NSLICE);
  const int lo = (int)blockIdx.y * S;
  const int hi = min((int)M, lo + S);
  int partial = 0;
  const int nt = (hi > lo) ? ((hi - lo + 255) >> 8) : 0;
  for (int ti = 0; ti < nt; ++ti) {
    int j = lo + ti * 256 + t;
    tile[t] = (j < hi) ? ckey[j] : 0ull;
    __syncthreads();
#pragma unroll 8
    for (int q = 0; q < 256; ++q) partial += (tile[q] > mykey) ? 1 : 0;
    __syncthreads();
  }
  if (p < (int)M) {
    unsigned int pack = (unsigned int)partial | (1u << 24);
    unsigned int old  = atomicAdd(&rank32[p], pack);
    unsigned int newv = old + pack;
    if ((newv >> 24) == NSLICE) {
      int r = (int)(newv & 0xFFFFFF);
      unsigned int orig = ~(unsigned int)(mykey & 0xffffffffull);
      sx1[r] = dx1[orig]; sy1[r] = dy1[orig];
      sx2[r] = dx2[orig]; sy2[r] = dy2[orig];
      sorig[r] = orig;
    }
  }
}

// ---------------------------------------------------------------- pairs -----
// Sparse suppression structure + per-column in-degree:
//   diag[r] = in-word bits; offd[r] = bits vs next word;
//   CSR rows rlJw/rlBits[rowbase(r)+k], k < cnt[r], for cw >= rw+2, bits != 0;
//   st[col] += 1 for every edge (low 16 bits = in-degree, high 16 = 0).
__global__ void __launch_bounds__(1024)
pairs_kernel(const float* __restrict__ sx1, const float* __restrict__ sy1,
             const float* __restrict__ sx2, const float* __restrict__ sy2,
             const unsigned int* __restrict__ Mc,
             unsigned long long* __restrict__ diag,
             unsigned long long* __restrict__ offd,
             unsigned int* __restrict__ cnt,
             unsigned short* __restrict__ rlJw,
             unsigned long long* __restrict__ rlBits,
             unsigned int* __restrict__ st) {
#pragma clang fp contract(off)
  const int M = (int)*Mc;
  const int W = (M + 63) >> 6;
  const int rw = (int)blockIdx.y;
  const int cwg = (int)blockIdx.x << 4;
  if (rw >= W || cwg >= W || cwg + 15 < rw) return;
  const int t = (int)threadIdx.x;
  const int g = t >> 6, l = t & 63;
  const int cw = cwg + g;
  __shared__ float cx1[1024], cy1[1024], cx2[1024], cy2[1024], car[1024];
  {
    int c = (cw << 6) + l;
    if (cw < W && c < M) {
      float a = sx1[c], b = sy1[c], d = sx2[c], e = sy2[c];
      cx1[t] = a; cy1[t] = b; cx2[t] = d; cy2[t] = e;
      car[t] = (d - a + 1.0f) * (e - b + 1.0f);
    }
  }
  __syncthreads();
  if (cw >= W || cw < rw) return;
  const int r = (rw << 6) + l;
  unsigned long long bits = 0ull;
  if (r < M) {
    float ax1 = sx1[r], ay1 = sy1[r], ax2 = sx2[r], ay2 = sy2[r];
    float aarea = (ax2 - ax1 + 1.0f) * (ay2 - ay1 + 1.0f);
    const int cmax = min(64, M - (cw << 6));
    const int sb = g << 6;
    for (int cc = 0; cc < cmax; ++cc) {
      int cg = (cw << 6) + cc;
      if (cg > r) {
        float xx1 = fmaxf(ax1, cx1[sb + cc]);
        float yy1 = fmaxf(ay1, cy1[sb + cc]);
        float xx2 = fminf(ax2, cx2[sb + cc]);
        float yy2 = fminf(ay2, cy2[sb + cc]);
        float ww = fmaxf(xx2 - xx1 + 1.0f, 0.0f);
        float hh = fmaxf(yy2 - yy1 + 1.0f, 0.0f);
        float inter = ww * hh;
        float iou = inter / (aarea + car[sb + cc] - inter);
        if (iou > NMS_TH) bits |= (1ull << cc);
      }
    }
  }
  if (cw == rw)            diag[r] = bits;
  else if (cw == rw + 1)   offd[r] = bits;
  else if (bits != 0ull) {
    unsigned k = atomicAdd(&cnt[r], 1u);
    unsigned b = rowbase_u((unsigned)r) + k;
    rlJw[b]   = (unsigned short)cw;
    rlBits[b] = bits;
  }
  // in-degree accumulation (every edge, all three cases)
  unsigned long long bb = bits;
  while (bb) {
    int c = __builtin_ctzll(bb); bb &= bb - 1ull;
    atomicAdd(&st[(cw << 6) + c], 1u);
  }
}

// ---------------------------------------------------------------- dag -------
// Exact greedy NMS as DAG wavefront (replaces the serial scan entirely).
// st[j] = (supCount << 16) | remainingIndeg. Resolving edge i->j with source
// status k: one atomicAdd(st[j], k ? 0xFFFF : -1). The unique thread that
// takes low half 1 -> 0 resolves j: SUP iff (high half incl. own contrib) != 0.
// Resolved boxes enqueue (LDS ring); each round expands the previous round's
// resolutions. Rounds = DAG depth (~tens). 16 waves -> full latency hiding.
__global__ void __launch_bounds__(1024)
dag_kernel(const unsigned long long* __restrict__ diag,
           const unsigned long long* __restrict__ offd,
           const unsigned int* __restrict__ cnt,
           const unsigned short* __restrict__ rlJw,
           const unsigned long long* __restrict__ rlBits,
           const unsigned int* __restrict__ sorig,
           const unsigned int* __restrict__ Mc,
           unsigned int* __restrict__ st,
           const float* __restrict__ dx1, const float* __restrict__ dy1,
           const float* __restrict__ dx2, const float* __restrict__ dy2,
           const float* __restrict__ dsc,
           float* __restrict__ out) {
  __shared__ unsigned short q[NA];              // each box enqueued exactly once
  __shared__ unsigned long long kmls[W_MAX];
  __shared__ int qTotal;
  const int t = (int)threadIdx.x;
  const int M = (int)*Mc;
  const int W = (M + 63) >> 6;

  for (int i = t; i < W_MAX; i += 1024) kmls[i] = 0ull;
  if (t == 0) qTotal = 0;
  __syncthreads();

  // init: boxes with no in-edges are KEPT and seed the wavefront
  for (int j = t; j < M; j += 1024) {
    if ((st[j] & 0xFFFFu) == 0u) {
      atomicOr(&kmls[j >> 6], 1ull << (j & 63));
      int idx = atomicAdd(&qTotal, 1);
      q[idx] = (unsigned short)j;
    }
  }
  __syncthreads();
  int rs = 0, re = qTotal;
  __syncthreads();

  while (rs < re) {
    for (int i = rs + t; i < re; i += 1024) {
      const int b = (int)q[i];
      const bool k = ((kmls[b >> 6] >> (b & 63)) & 1ull) != 0ull;
      const unsigned delta = k ? 0xFFFFu : 0xFFFFFFFFu;
      const int bw = b >> 6;

      unsigned long long bits = diag[b];
      int tbase = bw << 6;
      while (bits) {
        int c = __builtin_ctzll(bits); bits &= bits - 1ull;
        int j = tbase + c;
        unsigned old = atomicAdd(&st[j], delta);
        if ((old & 0xFFFFu) == 1u) {
          bool sup = ((old >> 16) + (k ? 1u : 0u)) != 0u;
          if (!sup) atomicOr(&kmls[j >> 6], 1ull << (j & 63));
          int idx = atomicAdd(&qTotal, 1);
          q[idx] = (unsigned short)j;
        }
      }
      if (bw + 1 < W) {
        bits = offd[b];
        tbase = (bw + 1) << 6;
        while (bits) {
          int c = __builtin_ctzll(bits); bits &= bits - 1ull;
          int j = tbase + c;
          unsigned old = atomicAdd(&st[j], delta);
          if ((old & 0xFFFFu) == 1u) {
            bool sup = ((old >> 16) + (k ? 1u : 0u)) != 0u;
            if (!sup) atomicOr(&kmls[j >> 6], 1ull << (j & 63));
            int idx = atomicAdd(&qTotal, 1);
            q[idx] = (unsigned short)j;
          }
        }
      }
      const unsigned cc = cnt[b];
      const unsigned rb = rowbase_u((unsigned)b);
      for (unsigned e = 0; e < cc; ++e) {
        int jw = (int)rlJw[rb + e];
        bits = rlBits[rb + e];
        tbase = jw << 6;
        while (bits) {
          int c = __builtin_ctzll(bits); bits &= bits - 1ull;
          int j = tbase + c;
          unsigned old = atomicAdd(&st[j], delta);
          if ((old & 0xFFFFu) == 1u) {
            bool sup = ((old >> 16) + (k ? 1u : 0u)) != 0u;
            if (!sup) atomicOr(&kmls[j >> 6], 1ull << (j & 63));
            int idx = atomicAdd(&qTotal, 1);
            q[idx] = (unsigned short)j;
          }
        }
      }
    }
    __syncthreads();            // all of this round's appends visible
    rs = re;
    re = qTotal;
    __syncthreads();            // all threads read qTotal before next appends
  }

  // scatter kept rows into the (pre-zeroed) output — all 16 waves
  for (int i = t; i < (W << 6); i += 1024) {
    if ((kmls[i >> 6] >> (i & 63)) & 1ull) {
      unsigned int orig = sorig[i];
      out[(size_t)orig * 5 + 0] = dx1[orig];
      out[(size_t)orig * 5 + 1] = dy1[orig];
      out[(size_t)orig * 5 + 2] = dx2[orig];
      out[(size_t)orig * 5 + 3] = dy2[orig];
      out[(size_t)orig * 5 + 4] = dsc[orig];
    }
  }
}

// ---------------------------------------------------------------- launch ----
extern "C" void kernel_launch(void* const* d_in, const int* in_sizes, int n_in,
                              void* d_out, int out_size, void* d_ws, size_t ws_size,
                              hipStream_t stream) {
  (void)in_sizes; (void)n_in; (void)out_size; (void)ws_size;

  Inputs in;
  for (int i = 0; i < 6; ++i) {
    in.cls[i] = (const float*)d_in[2 * i];
    in.reg[i] = (const float*)d_in[2 * i + 1];
  }

  char* ws = (char*)d_ws;
  size_t o = 0;
  float* dx1 = (float*)(ws + o); o += (size_t)NA * 4;
  float* dy1 = (float*)(ws + o); o += (size_t)NA * 4;
  float* dx2 = (float*)(ws + o); o += (size_t)NA * 4;
  float* dy2 = (float*)(ws + o); o += (size_t)NA * 4;
  float* dsc = (float*)(ws + o); o += (size_t)NA * 4;
  unsigned long long* ckey = (unsigned long long*)(ws + o); o += (size_t)NA * 8;
  float* sx1 = (float*)(ws + o); o += (size_t)NA * 4;
  float* sy1 = (float*)(ws + o); o += (size_t)NA * 4;
  float* sx2 = (float*)(ws + o); o += (size_t)NA * 4;
  float* sy2 = (float*)(ws + o); o += (size_t)NA * 4;
  unsigned int* sorig = (unsigned int*)(ws + o); o += (size_t)NA * 4;
  unsigned int* rank32 = (unsigned int*)(ws + o); o += (size_t)NA * 4;
  unsigned int* cnt = (unsigned int*)(ws + o); o += (size_t)NA * 4;
  unsigned int* st = (unsigned int*)(ws + o); o += (size_t)NA * 4;
  unsigned int* Mc = (unsigned int*)(ws + o); o += 64;
  o = (o + 511) & ~(size_t)511;
  unsigned long long* diag = (unsigned long long*)(ws + o); o += (size_t)NA * 8;
  unsigned long long* offd = (unsigned long long*)(ws + o); o += (size_t)NA * 8;
  unsigned long long* rlBits = (unsigned long long*)(ws + o); o += (size_t)TOT_ENT * 8;
  unsigned short* rlJw = (unsigned short*)(ws + o); o += (size_t)TOT_ENT * 2;

  const int nb = (N_TOTAL + 255) / 256;  // 86

  (void)hipMemsetAsync((void*)Mc, 0, 64, stream);
  decode_kernel<<<nb, 256, 0, stream>>>(in, dx1, dy1, dx2, dy2, dsc, ckey, Mc,
                                        rank32, cnt, st, (float*)d_out);
  rank_kernel<<<dim3(nb, NSLICE), 256, 0, stream>>>(ckey, Mc, dx1, dy1, dx2, dy2,
                                                    sx1, sy1, sx2, sy2, sorig,
                                                    rank32);
  pairs_kernel<<<dim3(22, W_MAX), 1024, 0, stream>>>(sx1, sy1, sx2, sy2, Mc,
                                                     diag, offd, cnt, rlJw, rlBits,
                                                     st);
  dag_kernel<<<1, 1024, 0, stream>>>(diag, offd, cnt, rlJw, rlBits, sorig, Mc, st,
                                     dx1, dy1, dx2, dy2, dsc, (float*)d_out);
}